// Round 2
// baseline (216.781 us; speedup 1.0000x reference)
//
#include <hip/hip_runtime.h>
#include <stdint.h>

#define BB 4096
#define TT 200
#define DD 128
#define HH 128

typedef __attribute__((ext_vector_type(8))) short bf16x8;
typedef __attribute__((ext_vector_type(4))) float f32x4;

__device__ __forceinline__ short f2bf(float f) {
    uint32_t u = __builtin_bit_cast(uint32_t, f);
    u += 0x7fffu + ((u >> 16) & 1u);   // RNE
    return (short)(u >> 16);
}
__device__ __forceinline__ uint32_t pk2(float a, float b) {
    uint32_t r;
    asm("v_cvt_pk_bf16_f32 %0, %1, %2" : "=v"(r) : "v"(a), "v"(b));
    return r;
}
__device__ __forceinline__ float sigm(float x) {
    return __builtin_amdgcn_rcpf(1.0f + __expf(-x));
}
__device__ __forceinline__ float tanhf_(float x) {
    return 2.0f * __builtin_amdgcn_rcpf(1.0f + __expf(-2.0f * x)) - 1.0f;
}
// LDS-only barrier: drain lgkm (our ds ops), NOT vmcnt -> global prefetch
// stays in flight across the barrier (T4 counted-vmcnt lesson).
__device__ __forceinline__ void bar_lds() {
    asm volatile("s_waitcnt lgkmcnt(0)" ::: "memory");
    __builtin_amdgcn_sched_barrier(0);
    __builtin_amdgcn_s_barrier();
    __builtin_amdgcn_sched_barrier(0);
}

// 4-wave variant: each wave owns 32 output cols (2 col-tiles of 16), halving
// the per-CU LDS broadcast traffic (the round-1 bottleneck: 8 waves x 12
// ds_read_b128/step ~= 1150 cyc on the CU-shared LDS pipe). Per-SIMD VALU/MFMA
// totals unchanged; weight frags double -> ~350 VGPR -> 1 wave/SIMD
// (__launch_bounds__(256,1), 512-VGPR budget).
//
// LDS layout: [16 rows][16 granules] of bf16x8 (16B granules, 256B row stride),
// granule XOR-swizzled by (row&7); fragment reads are conflict-free b128.

#define STEP(T, XR0, XR1) { \
    const int sn_ = ((T) + 1) & 1; \
    *(uint4*)&xbuf[sn_][xrow][xg_swz] = \
        make_uint4(pk2(XR0.x, XR0.y), pk2(XR0.z, XR0.w), \
                   pk2(XR1.x, XR1.y), pk2(XR1.z, XR1.w)); \
    { const int t3_ = ((T) + 3 < TT) ? (T) + 3 : TT - 1; \
      XR0 = *(const float4*)(xsrc + (size_t)t3_ * DD); \
      XR1 = *(const float4*)(xsrc + (size_t)t3_ * DD + 4); } \
    bf16x8 hf_[4]; \
    _Pragma("unroll") \
    for (int kt = 0; kt < 4; ++kt) hf_[kt] = hrow[fg[kt]]; \
    f32x4 az_[2], ar_[2]; \
    _Pragma("unroll") \
    for (int ct = 0; ct < 2; ++ct) { az_[ct] = pz[ct]; ar_[ct] = pr[ct]; } \
    _Pragma("unroll") \
    for (int kt = 0; kt < 4; ++kt) { \
        _Pragma("unroll") \
        for (int ct = 0; ct < 2; ++ct) { \
            az_[ct] = __builtin_amdgcn_mfma_f32_16x16x32_bf16(Wf[0][1][kt][ct], hf_[kt], az_[ct], 0, 0, 0); \
            ar_[ct] = __builtin_amdgcn_mfma_f32_16x16x32_bf16(Wf[1][1][kt][ct], hf_[kt], ar_[ct], 0, 0, 0); \
        } \
    } \
    f32x4 zv_[2], rhv_[2]; \
    _Pragma("unroll") \
    for (int ct = 0; ct < 2; ++ct) { \
        _Pragma("unroll") \
        for (int r = 0; r < 4; ++r) { \
            zv_[ct][r]  = sigm(az_[ct][r]); \
            rhv_[ct][r] = sigm(ar_[ct][r]) * hreg[ct][r]; \
        } \
        *(uint2*)((short*)&rhbuf[c][gout[ct]] + ohalf) = \
            make_uint2(pk2(rhv_[ct][0], rhv_[ct][1]), pk2(rhv_[ct][2], rhv_[ct][3])); \
    } \
    bar_lds(); \
    const float a_c_ = attbuf[c][(T)]; \
    bf16x8 rf_[4], xf2_[4]; \
    { const bf16x8* xp2_ = &xbuf[sn_][c][0]; \
      _Pragma("unroll") \
      for (int kt = 0; kt < 4; ++kt) { \
          rf_[kt]  = rhrow[fg[kt]]; \
          xf2_[kt] = xp2_[fg[kt]]; \
      } } \
    f32x4 ah_[2]; \
    _Pragma("unroll") \
    for (int ct = 0; ct < 2; ++ct) ah_[ct] = ph[ct]; \
    _Pragma("unroll") \
    for (int kt = 0; kt < 4; ++kt) { \
        _Pragma("unroll") \
        for (int ct = 0; ct < 2; ++ct) \
            ah_[ct] = __builtin_amdgcn_mfma_f32_16x16x32_bf16(Wf[2][1][kt][ct], rf_[kt], ah_[ct], 0, 0, 0); \
    } \
    _Pragma("unroll") \
    for (int ct = 0; ct < 2; ++ct) { pz[ct] = bzv[ct]; pr[ct] = brv[ct]; ph[ct] = bhv[ct]; } \
    _Pragma("unroll") \
    for (int kt = 0; kt < 4; ++kt) { \
        _Pragma("unroll") \
        for (int ct = 0; ct < 2; ++ct) { \
            pz[ct] = __builtin_amdgcn_mfma_f32_16x16x32_bf16(Wf[0][0][kt][ct], xf2_[kt], pz[ct], 0, 0, 0); \
            pr[ct] = __builtin_amdgcn_mfma_f32_16x16x32_bf16(Wf[1][0][kt][ct], xf2_[kt], pr[ct], 0, 0, 0); \
            ph[ct] = __builtin_amdgcn_mfma_f32_16x16x32_bf16(Wf[2][0][kt][ct], xf2_[kt], ph[ct], 0, 0, 0); \
        } \
    } \
    _Pragma("unroll") \
    for (int ct = 0; ct < 2; ++ct) { \
        _Pragma("unroll") \
        for (int r = 0; r < 4; ++r) { \
            float ht_ = tanhf_(ah_[ct][r]); \
            float zp_ = a_c_ * zv_[ct][r]; \
            hreg[ct][r] = __builtin_fmaf(zp_, ht_ - hreg[ct][r], hreg[ct][r]); \
        } \
        *(uint2*)((short*)&hbuf[c][gout[ct]] + ohalf) = \
            make_uint2(pk2(hreg[ct][0], hreg[ct][1]), pk2(hreg[ct][2], hreg[ct][3])); \
    } \
    bar_lds(); \
}

__global__ __launch_bounds__(256, 1) void augru_kernel(
    const float* __restrict__ inp,   // [B,T,D]
    const float* __restrict__ att,   // [B,T]
    const float* __restrict__ h0,    // [B,H]
    const float* __restrict__ Wz, const float* __restrict__ bz,
    const float* __restrict__ Wr, const float* __restrict__ br,
    const float* __restrict__ Wh, const float* __restrict__ bh,
    float* __restrict__ out)         // [B,H]
{
    __shared__ bf16x8 xbuf[2][16][16];   // x(t) bf16, swizzled granules
    __shared__ bf16x8 hbuf[16][16];      // h(t) bf16 mirror, swizzled
    __shared__ bf16x8 rhbuf[16][16];     // r*h staging, swizzled
    __shared__ float attbuf[16][201];    // whole att tile, padded (conflict-free)

    const int tid  = threadIdx.x;
    const int wave = tid >> 6;           // 0..3
    const int lane = tid & 63;
    const int c    = lane & 15;          // batch row
    const int grp  = lane >> 4;          // k-group
    const int wbase = wave * 32;         // this wave's 32 output cols
    const int rowbase = blockIdx.x * 16;

    // swizzle constants (loop-invariant)
    const int swz = c & 7;
    const int fg[4] = { (0 + grp) ^ swz, (4 + grp) ^ swz,
                        (8 + grp) ^ swz, (12 + grp) ^ swz };
    const int oc[2]   = { wbase + grp * 4, wbase + 16 + grp * 4 };
    const int gout[2] = { (4 * wave + (grp >> 1)) ^ swz,
                          (4 * wave + 2 + (grp >> 1)) ^ swz };
    const int ohalf = (grp & 1) * 4;     // short offset within granule
    const bf16x8* hrow  = &hbuf[c][0];
    const bf16x8* rhrow = &rhbuf[c][0];

    // ---------------- weights -> register fragments ----------------
    bf16x8 Wf[3][2][4][2];
    {
        const float* Wp[3] = {Wz, Wr, Wh};
        #pragma unroll
        for (int g3 = 0; g3 < 3; ++g3) {
            #pragma unroll
            for (int p = 0; p < 2; ++p) {
                #pragma unroll
                for (int kt = 0; kt < 4; ++kt) {
                    #pragma unroll
                    for (int ct = 0; ct < 2; ++ct) {
                        bf16x8 v;
                        #pragma unroll
                        for (int j = 0; j < 8; ++j) {
                            int k = p * 128 + kt * 32 + grp * 8 + j;
                            v[j] = f2bf(Wp[g3][(size_t)k * HH + wbase + ct * 16 + c]);
                        }
                        Wf[g3][p][kt][ct] = v;
                    }
                }
            }
        }
    }
    f32x4 bzv[2], brv[2], bhv[2];
    #pragma unroll
    for (int ct = 0; ct < 2; ++ct)
        #pragma unroll
        for (int r = 0; r < 4; ++r) {
            bzv[ct][r] = bz[oc[ct] + r];
            brv[ct][r] = br[oc[ct] + r];
            bhv[ct][r] = bh[oc[ct] + r];
        }

    // ---------------- att tile -> LDS (one-time, coalesced) ----------------
    for (int idx = tid; idx < 16 * TT; idx += 256)
        attbuf[idx / TT][idx % TT] = att[(size_t)rowbase * TT + idx];

    // ---------------- h state ----------------
    f32x4 hreg[2];
    #pragma unroll
    for (int ct = 0; ct < 2; ++ct) {
        float4 hv = *(const float4*)&h0[(size_t)(rowbase + c) * HH + oc[ct]];
        hreg[ct][0] = hv.x; hreg[ct][1] = hv.y; hreg[ct][2] = hv.z; hreg[ct][3] = hv.w;
        *(uint2*)((short*)&hbuf[c][gout[ct]] + ohalf) =
            make_uint2(pk2(hv.x, hv.y), pk2(hv.z, hv.w));
    }

    // ---------------- x(0) stage; prefetch x(1), x(2) ----------------
    // thread (xrow, 8-col chunk): stages a full bf16x8 granule per t.
    const int xrow = tid >> 4;            // 0..15
    const int xc8  = (tid & 15) * 8;      // 8-float chunk
    const int xg_swz = (tid & 15) ^ (xrow & 7);
    const float* xsrc = inp + ((size_t)(rowbase + xrow) * TT) * DD + xc8;
    {
        float4 x0a = *(const float4*)(xsrc);
        float4 x0b = *(const float4*)(xsrc + 4);
        *(uint4*)&xbuf[0][xrow][xg_swz] =
            make_uint4(pk2(x0a.x, x0a.y), pk2(x0a.z, x0a.w),
                       pk2(x0b.x, x0b.y), pk2(x0b.z, x0b.w));
    }
    float4 xrA0 = *(const float4*)(xsrc + DD);
    float4 xrA1 = *(const float4*)(xsrc + DD + 4);
    float4 xrB0 = *(const float4*)(xsrc + 2 * DD);
    float4 xrB1 = *(const float4*)(xsrc + 2 * DD + 4);
    __syncthreads();

    // pre(0): feed-forward x-parts
    f32x4 pz[2], pr[2], ph[2];
    #pragma unroll
    for (int ct = 0; ct < 2; ++ct) { pz[ct] = bzv[ct]; pr[ct] = brv[ct]; ph[ct] = bhv[ct]; }
    {
        const bf16x8* x0p = &xbuf[0][c][0];
        bf16x8 xf[4];
        #pragma unroll
        for (int kt = 0; kt < 4; ++kt) xf[kt] = x0p[fg[kt]];
        #pragma unroll
        for (int kt = 0; kt < 4; ++kt) {
            #pragma unroll
            for (int ct = 0; ct < 2; ++ct) {
                pz[ct] = __builtin_amdgcn_mfma_f32_16x16x32_bf16(Wf[0][0][kt][ct], xf[kt], pz[ct], 0, 0, 0);
                pr[ct] = __builtin_amdgcn_mfma_f32_16x16x32_bf16(Wf[1][0][kt][ct], xf[kt], pr[ct], 0, 0, 0);
                ph[ct] = __builtin_amdgcn_mfma_f32_16x16x32_bf16(Wf[2][0][kt][ct], xf[kt], ph[ct], 0, 0, 0);
            }
        }
    }

    // ---------------- scan (unrolled x2: A regs even steps, B regs odd) ----------------
    for (int t = 0; t < TT; t += 2) {
        STEP(t, xrA0, xrA1);
        STEP(t + 1, xrB0, xrB1);
    }

    // ---------------- store h_final ----------------
    #pragma unroll
    for (int ct = 0; ct < 2; ++ct) {
        float4 o; o.x = hreg[ct][0]; o.y = hreg[ct][1]; o.z = hreg[ct][2]; o.w = hreg[ct][3];
        *(float4*)&out[(size_t)(rowbase + c) * HH + oc[ct]] = o;
    }
}

extern "C" void kernel_launch(void* const* d_in, const int* in_sizes, int n_in,
                              void* d_out, int out_size, void* d_ws, size_t ws_size,
                              hipStream_t stream) {
    const float* inp = (const float*)d_in[0];
    const float* att = (const float*)d_in[1];
    const float* h0  = (const float*)d_in[2];
    const float* Wz  = (const float*)d_in[3];
    const float* bz  = (const float*)d_in[4];
    const float* Wr  = (const float*)d_in[5];
    const float* br  = (const float*)d_in[6];
    const float* Wh  = (const float*)d_in[7];
    const float* bh  = (const float*)d_in[8];
    float* out = (float*)d_out;

    dim3 grid(BB / 16), block(256);
    augru_kernel<<<grid, block, 0, stream>>>(inp, att, h0, Wz, bz, Wr, br, Wh, bh, out);
}